// Round 16
// baseline (237.471 us; speedup 1.0000x reference)
//
#include <hip/hip_runtime.h>
#include <stdint.h>

// irreps linear: 128x0e+128x1o+128x2e, per-block y[z,w,i] = a * sum_u W[u,w] x[z,u,i]
// r16 = r13 (fused full-row WGs, plain dense stores, best 191.1us) with
// TM 16 -> 32: halves the number of tile-rounds (24.4 -> 12.2 per WG), i.e.
// halves the per-round fixed overhead (vmcnt-wait pipeline drain, barrier
// convergence) which the arithmetic says is ~1.8us of the 7.8us round. All
// per-instruction access patterns unchanged. LDS dbuf 2x73728 = 147456B,
// 1 WG/CU, 16 waves, VGPR target <=128 at (1024,4).

#define NROWS 100000
#define ROWLEN 1152

typedef __attribute__((ext_vector_type(8))) short bf16x8;
typedef __attribute__((ext_vector_type(4))) float f32x4;
typedef __attribute__((ext_vector_type(4))) ushort u16x4;
typedef float f32x4u __attribute__((ext_vector_type(4), aligned(4)));
typedef float f32x2u __attribute__((ext_vector_type(2), aligned(4)));

__device__ __forceinline__ ushort f2b(float f) {
  union { float f; uint32_t u; } v; v.f = f;
  uint32_t r = v.u + 0x7FFFu + ((v.u >> 16) & 1u);  // RNE; inputs finite
  return (ushort)(r >> 16);
}

constexpr int TM     = 32;
constexpr int NTILES = NROWS / TM;   // 3125 exactly -> no guards anywhere
constexpr int NWGS   = 256;          // 1 WG/CU
constexpr int BUFB   = 288 * 256;    // 73728 B: 288 m-rows (32 D1 + 96 D3 + 160 D5)
constexpr float ALPHA = 0.088388347648318447f;  // 128^-0.5

// LDS byte for (m-row, 4-u chunk cc in 0..31), 8B granule; 16B-chunk XOR swizzle.
__device__ __forceinline__ int lbyte8(int m, int cc) {
  return m * 256 + ((((cc >> 1) ^ (m & 7)) << 4) | ((cc & 1) << 3));
}

// ---- staging: class A (tid<512): D1+D3 groups; class B: D5 groups.
// TM=32 -> 1024 groups per class; each thread handles p=0,1: g = p*512 + sg,
// row szl = g>>5 (0..31), u-chunk cc = g&31.
// m-rows: D1 m=szl; D3 m=32+i*32+szl; D5 m=128+i*32+szl.
__device__ __forceinline__ void stage_load(const float* __restrict__ x, int t,
                                           bool clb, int sg, f32x4 (&vf)[2][5])
{
  #pragma unroll
  for (int p = 0; p < 2; ++p) {
    const int g   = p * 512 + sg;
    const int szl = g >> 5, scc = g & 31;
    const float* row = x + (size_t)(t * TM + szl) * ROWLEN;
    if (!clb) {
      vf[p][0] = *(const f32x4*)(row + scc * 4);       // D1
      const float* r3 = row + 128 + scc * 12;          // D3: 12 floats
      vf[p][1] = *(const f32x4*)(r3);
      vf[p][2] = *(const f32x4*)(r3 + 4);
      vf[p][3] = *(const f32x4*)(r3 + 8);
    } else {
      const float* r5 = row + 512 + scc * 20;          // D5: 20 floats
      #pragma unroll
      for (int j = 0; j < 5; ++j) vf[p][j] = *(const f32x4*)(r5 + 4 * j);
    }
  }
}

__device__ __forceinline__ void stage_write(char* __restrict__ buf, bool clb,
                                            int sg, f32x4 (&vf)[2][5])
{
  #pragma unroll
  for (int p = 0; p < 2; ++p) {
    const int g   = p * 512 + sg;
    const int szl = g >> 5, scc = g & 31;
    if (!clb) {
      u16x4 p1;
      #pragma unroll
      for (int k = 0; k < 4; ++k) p1[k] = f2b(vf[p][0][k]);
      *(u16x4*)(buf + lbyte8(szl, scc)) = p1;          // D1
      #pragma unroll
      for (int i = 0; i < 3; ++i) {                    // D3
        u16x4 pk;
        #pragma unroll
        for (int u = 0; u < 4; ++u) {
          int k = 3 * u + i;                           // compile-time
          pk[u] = f2b(vf[p][1 + (k >> 2)][k & 3]);
        }
        *(u16x4*)(buf + lbyte8(32 + i * 32 + szl, scc)) = pk;
      }
    } else {
      #pragma unroll
      for (int i = 0; i < 5; ++i) {                    // D5
        u16x4 pk;
        #pragma unroll
        for (int u = 0; u < 4; ++u) {
          int k = 5 * u + i;                           // compile-time
          pk[u] = f2b(vf[p][k >> 2][k & 3]);
        }
        *(u16x4*)(buf + lbyte8(128 + i * 32 + szl, scc)) = pk;
      }
    }
  }
}

__global__ __launch_bounds__(1024, 4)
void linear_irreps_kernel(const float* __restrict__ x, const float* __restrict__ w,
                          float* __restrict__ out)
{
  __shared__ __align__(16) char lds[2 * BUFB];         // 147456 B

  const int tid  = threadIdx.x;
  const int lane = tid & 63;
  const int wv   = tid >> 6;            // 0..15
  const int l15  = lane & 15;
  const int kq   = (lane >> 4) & 3;
  const int kr   = kq << 3;
  const int mx7  = l15 & 7;             // (m & 7) for all m = base16 + l15
  const int h    = wv & 1;              // 0: D1+D3 m-tiles, 1: D5 m-tiles
  const int n    = ((wv >> 1) << 4) + l15;   // out/W column 0..127
  const bool clb = tid >= 512;
  const int sg   = tid & 511;

  // ---- W -> registers once (ALPHA folded). h0: D1+D3 blocks; h1: D5 block.
  bf16x8 bfr[2][4];
  if (h == 0) {
    #pragma unroll
    for (int ks = 0; ks < 4; ++ks)
      #pragma unroll
      for (int j = 0; j < 8; ++j) {
        bfr[0][ks][j] = (short)f2b(w[(ks * 32 + kr + j) * 128 + n] * ALPHA);
        bfr[1][ks][j] = (short)f2b(w[16384 + (ks * 32 + kr + j) * 128 + n] * ALPHA);
      }
  } else {
    #pragma unroll
    for (int ks = 0; ks < 4; ++ks)
      #pragma unroll
      for (int j = 0; j < 8; ++j)
        bfr[0][ks][j] = (short)f2b(w[32768 + (ks * 32 + kr + j) * 128 + n] * ALPHA);
  }

  // ---- prologue: stage tile t0 ----
  const int t0 = blockIdx.x;
  f32x4 vf[2][5];
  stage_load(x, t0, clb, sg, vf);
  stage_write(lds, clb, sg, vf);
  __syncthreads();

  int cur = 0;
  for (int t = t0; t < NTILES; t += NWGS) {
    char* bc = lds + (cur ? BUFB : 0);
    char* bn = lds + (cur ? 0 : BUFB);
    const int tn = t + NWGS;
    const bool have = tn < NTILES;

    // 1. issue next tile's global loads (hide under MFMA)
    if (have) stage_load(x, tn, clb, sg, vf);

    // 2. MFMA on current buffer
    f32x4 acc[10];
    #pragma unroll
    for (int i = 0; i < 10; ++i) acc[i] = f32x4{0.f, 0.f, 0.f, 0.f};
    if (h == 0) {
      // acc[0..1]: D1 tiles (m base 0,16); acc[2+tt]: D3 tiles tt=0..5 (m 32+16tt)
      #pragma unroll
      for (int ks = 0; ks < 4; ++ks) {
        const int cb = ((ks * 4 + kq) ^ mx7) << 4;
        #pragma unroll
        for (int mt = 0; mt < 2; ++mt) {
          bf16x8 a = *(const bf16x8*)(bc + (mt * 16 + l15) * 256 + cb);
          acc[mt] = __builtin_amdgcn_mfma_f32_16x16x32_bf16(a, bfr[0][ks], acc[mt], 0, 0, 0);
        }
        #pragma unroll
        for (int tt = 0; tt < 6; ++tt) {
          bf16x8 a = *(const bf16x8*)(bc + (32 + tt * 16 + l15) * 256 + cb);
          acc[2 + tt] = __builtin_amdgcn_mfma_f32_16x16x32_bf16(a, bfr[1][ks], acc[2 + tt], 0, 0, 0);
        }
      }
    } else {
      // acc[tt]: D5 tiles tt=0..9 (m 128+16tt)
      #pragma unroll
      for (int ks = 0; ks < 4; ++ks) {
        const int cb = ((ks * 4 + kq) ^ mx7) << 4;
        #pragma unroll
        for (int tt = 0; tt < 10; ++tt) {
          bf16x8 a = *(const bf16x8*)(bc + (128 + tt * 16 + l15) * 256 + cb);
          acc[tt] = __builtin_amdgcn_mfma_f32_16x16x32_bf16(a, bfr[0][ks], acc[tt], 0, 0, 0);
        }
      }
    }

    // 3. convert + LDS-write next tile (loads have landed)
    if (have) stage_write(bn, clb, sg, vf);

    // 4. store tile t (dense per-lane spans, plain stores)
    // row zl = half*16 + kq*4 + r; D3/D5 tile index tt = i*2 + half.
    const int z0 = t * TM;
    if (h == 0) {
      #pragma unroll
      for (int half = 0; half < 2; ++half)
        #pragma unroll
        for (int r = 0; r < 4; ++r) {
          int z = z0 + half * 16 + (kq << 2) + r;
          float* orow = out + (size_t)z * ROWLEN;
          orow[n] = acc[half][r];
          f32x2u v2 = { acc[2 + half][r], acc[4 + half][r] };
          *(f32x2u*)(orow + 128 + n * 3) = v2;
          orow[128 + n * 3 + 2] = acc[6 + half][r];
        }
    } else {
      #pragma unroll
      for (int half = 0; half < 2; ++half)
        #pragma unroll
        for (int r = 0; r < 4; ++r) {
          int z = z0 + half * 16 + (kq << 2) + r;
          float* orow = out + (size_t)z * ROWLEN;
          f32x4u v4 = { acc[half][r], acc[2 + half][r], acc[4 + half][r], acc[6 + half][r] };
          *(f32x4u*)(orow + 512 + n * 5) = v4;
          orow[512 + n * 5 + 4] = acc[8 + half][r];
        }
    }

    __syncthreads();
    cur ^= 1;
  }
}

extern "C" void kernel_launch(void* const* d_in, const int* in_sizes, int n_in,
                              void* d_out, int out_size, void* d_ws, size_t ws_size,
                              hipStream_t stream) {
  const float* x = (const float*)d_in[0];
  const float* w = (const float*)d_in[1];
  float* out = (float*)d_out;
  (void)in_sizes; (void)n_in; (void)out_size; (void)d_ws; (void)ws_size;
  dim3 grid(NWGS);
  dim3 block(1024);
  hipLaunchKernelGGL(linear_irreps_kernel, grid, block, 0, stream, x, w, out);
}

// Round 17
// 190.584 us; speedup vs baseline: 1.2460x; 1.2460x over previous
//
#include <hip/hip_runtime.h>
#include <stdint.h>

// irreps linear: 128x0e+128x1o+128x2e, per-block y[z,w,i] = a * sum_u W[u,w] x[z,u,i]
// FINAL (= r13, best measured 191.1us): fused full-row WGs, plain stores.
// One 1024-thread WG owns 16 complete rows per tile (contiguous 73.7KB read +
// write -> single DRAM-row activation per row), 1 WG/CU, W in regs, dbuf LDS,
// register prefetch issued before MFMA and consumed after, dense per-lane
// plain stores (NT hints inflate WRITE_SIZE 45% on this structure - r12),
// one __syncthreads per tile.
// Probed and rejected: extra occupancy (r5/r15 null), NT stores (r8 null,
// r12 hurt), lgkm-only barrier (r9 null), coalesced-load+scatter-LDS (r11
// regress), out-staging via LDS (r4 regress), TM=32 (r16 regress, VGPR
// pressure), forced 8 waves/SIMD (r14 regress, spills).

#define NROWS 100000
#define ROWLEN 1152

typedef __attribute__((ext_vector_type(8))) short bf16x8;
typedef __attribute__((ext_vector_type(4))) float f32x4;
typedef __attribute__((ext_vector_type(4))) ushort u16x4;
typedef float f32x4u __attribute__((ext_vector_type(4), aligned(4)));
typedef float f32x2u __attribute__((ext_vector_type(2), aligned(4)));

__device__ __forceinline__ ushort f2b(float f) {
  union { float f; uint32_t u; } v; v.f = f;
  uint32_t r = v.u + 0x7FFFu + ((v.u >> 16) & 1u);  // RNE; inputs finite
  return (ushort)(r >> 16);
}

constexpr int TM     = 16;
constexpr int NTILES = NROWS / TM;   // 6250 exactly -> no guards anywhere
constexpr int NWGS   = 256;          // 1 WG/CU
constexpr int BUFB   = 144 * 256;    // 36864 B: 144 m-rows (16 D1 + 48 D3 + 80 D5)
constexpr float ALPHA = 0.088388347648318447f;  // 128^-0.5

// LDS byte for (m-row, 4-u chunk cc in 0..31), 8B granule; 16B-chunk XOR swizzle.
__device__ __forceinline__ int lbyte8(int m, int cc) {
  return m * 256 + ((((cc >> 1) ^ (m & 7)) << 4) | ((cc & 1) << 3));
}

// ---- staging: class A (tid<512): one D1 group + one D3 group; class B: one D5
// group. Group g: row szl = g>>5, u-chunk cc = g&31.
__device__ __forceinline__ void stage_load(const float* __restrict__ x, int t,
                                           bool clb, int szl, int scc,
                                           f32x4 (&vf)[5])
{
  const float* row = x + (size_t)(t * TM + szl) * ROWLEN;
  if (!clb) {
    vf[0] = *(const f32x4*)(row + scc * 4);            // D1: u = 4cc..4cc+3
    const float* r3 = row + 128 + scc * 12;            // D3: 12 floats
    vf[1] = *(const f32x4*)(r3);
    vf[2] = *(const f32x4*)(r3 + 4);
    vf[3] = *(const f32x4*)(r3 + 8);
  } else {
    const float* r5 = row + 512 + scc * 20;            // D5: 20 floats
    #pragma unroll
    for (int j = 0; j < 5; ++j) vf[j] = *(const f32x4*)(r5 + 4 * j);
  }
}

__device__ __forceinline__ void stage_write(char* __restrict__ buf, bool clb,
                                            int szl, int scc, f32x4 (&vf)[5])
{
  if (!clb) {
    u16x4 p1;
    #pragma unroll
    for (int k = 0; k < 4; ++k) p1[k] = f2b(vf[0][k]);
    *(u16x4*)(buf + lbyte8(szl, scc)) = p1;            // D1: m = szl
    #pragma unroll
    for (int i = 0; i < 3; ++i) {                      // D3: m = 16 + i*16 + szl
      u16x4 pk;
      #pragma unroll
      for (int u = 0; u < 4; ++u) {
        int k = 3 * u + i;                             // compile-time
        pk[u] = f2b(vf[1 + (k >> 2)][k & 3]);
      }
      *(u16x4*)(buf + lbyte8(16 + i * 16 + szl, scc)) = pk;
    }
  } else {
    #pragma unroll
    for (int i = 0; i < 5; ++i) {                      // D5: m = 64 + i*16 + szl
      u16x4 pk;
      #pragma unroll
      for (int u = 0; u < 4; ++u) {
        int k = 5 * u + i;                             // compile-time
        pk[u] = f2b(vf[k >> 2][k & 3]);
      }
      *(u16x4*)(buf + lbyte8(64 + i * 16 + szl, scc)) = pk;
    }
  }
}

__global__ __launch_bounds__(1024, 4)
void linear_irreps_kernel(const float* __restrict__ x, const float* __restrict__ w,
                          float* __restrict__ out)
{
  __shared__ __align__(16) char lds[2 * BUFB];         // 73728 B

  const int tid  = threadIdx.x;
  const int lane = tid & 63;
  const int wv   = tid >> 6;            // 0..15
  const int l15  = lane & 15;
  const int kq   = (lane >> 4) & 3;
  const int kr   = kq << 3;
  const int mx7  = l15 & 7;             // (m & 7) for all m = base16 + l15
  const int h    = wv & 1;              // 0: D1+D3 m-tiles, 1: D5 m-tiles
  const int n    = ((wv >> 1) << 4) + l15;   // out/W column 0..127
  const bool clb = tid >= 512;
  const int sg   = clb ? tid - 512 : tid;
  const int szl  = sg >> 5;
  const int scc  = sg & 31;

  // ---- W -> registers once (ALPHA folded). h0: D1+D3 blocks; h1: D5 block.
  bf16x8 bfr[2][4];
  if (h == 0) {
    #pragma unroll
    for (int ks = 0; ks < 4; ++ks)
      #pragma unroll
      for (int j = 0; j < 8; ++j) {
        bfr[0][ks][j] = (short)f2b(w[(ks * 32 + kr + j) * 128 + n] * ALPHA);
        bfr[1][ks][j] = (short)f2b(w[16384 + (ks * 32 + kr + j) * 128 + n] * ALPHA);
      }
  } else {
    #pragma unroll
    for (int ks = 0; ks < 4; ++ks)
      #pragma unroll
      for (int j = 0; j < 8; ++j)
        bfr[0][ks][j] = (short)f2b(w[32768 + (ks * 32 + kr + j) * 128 + n] * ALPHA);
  }

  // ---- prologue: stage tile t0 ----
  const int t0 = blockIdx.x;
  f32x4 vf[5];
  stage_load(x, t0, clb, szl, scc, vf);
  stage_write(lds, clb, szl, scc, vf);
  __syncthreads();

  int cur = 0;
  for (int t = t0; t < NTILES; t += NWGS) {
    char* bc = lds + (cur ? BUFB : 0);
    char* bn = lds + (cur ? 0 : BUFB);
    const int tn = t + NWGS;
    const bool have = tn < NTILES;

    // 1. issue next tile's global loads (hide under MFMA)
    if (have) stage_load(x, tn, clb, szl, scc, vf);

    // 2. MFMA on current buffer
    f32x4 acc[5];
    #pragma unroll
    for (int i = 0; i < 5; ++i) acc[i] = f32x4{0.f, 0.f, 0.f, 0.f};
    if (h == 0) {
      #pragma unroll
      for (int ks = 0; ks < 4; ++ks) {
        const int cb = ((ks * 4 + kq) ^ mx7) << 4;
        bf16x8 a0 = *(const bf16x8*)(bc + (l15)       * 256 + cb);
        bf16x8 a1 = *(const bf16x8*)(bc + (16  + l15) * 256 + cb);
        bf16x8 a2 = *(const bf16x8*)(bc + (32  + l15) * 256 + cb);
        bf16x8 a3 = *(const bf16x8*)(bc + (48  + l15) * 256 + cb);
        acc[0] = __builtin_amdgcn_mfma_f32_16x16x32_bf16(a0, bfr[0][ks], acc[0], 0, 0, 0);
        acc[1] = __builtin_amdgcn_mfma_f32_16x16x32_bf16(a1, bfr[1][ks], acc[1], 0, 0, 0);
        acc[2] = __builtin_amdgcn_mfma_f32_16x16x32_bf16(a2, bfr[1][ks], acc[2], 0, 0, 0);
        acc[3] = __builtin_amdgcn_mfma_f32_16x16x32_bf16(a3, bfr[1][ks], acc[3], 0, 0, 0);
      }
    } else {
      #pragma unroll
      for (int ks = 0; ks < 4; ++ks) {
        const int cb = ((ks * 4 + kq) ^ mx7) << 4;
        #pragma unroll
        for (int i = 0; i < 5; ++i) {
          bf16x8 a = *(const bf16x8*)(bc + (64 + i * 16 + l15) * 256 + cb);
          acc[i] = __builtin_amdgcn_mfma_f32_16x16x32_bf16(a, bfr[0][ks], acc[i], 0, 0, 0);
        }
      }
    }

    // 3. convert + LDS-write next tile (loads have landed)
    if (have) stage_write(bn, clb, szl, scc, vf);

    // 4. store tile t (dense per-lane spans, plain stores)
    const int z0 = t * TM;
    if (h == 0) {
      #pragma unroll
      for (int r = 0; r < 4; ++r) {
        int z = z0 + (kq << 2) + r;
        float* orow = out + (size_t)z * ROWLEN;
        orow[n] = acc[0][r];
        f32x2u v2 = { acc[1][r], acc[2][r] };
        *(f32x2u*)(orow + 128 + n * 3) = v2;
        orow[128 + n * 3 + 2] = acc[3][r];
      }
    } else {
      #pragma unroll
      for (int r = 0; r < 4; ++r) {
        int z = z0 + (kq << 2) + r;
        float* orow = out + (size_t)z * ROWLEN;
        f32x4u v4 = { acc[0][r], acc[1][r], acc[2][r], acc[3][r] };
        *(f32x4u*)(orow + 512 + n * 5) = v4;
        orow[512 + n * 5 + 4] = acc[4][r];
      }
    }

    __syncthreads();
    cur ^= 1;
  }
}

extern "C" void kernel_launch(void* const* d_in, const int* in_sizes, int n_in,
                              void* d_out, int out_size, void* d_ws, size_t ws_size,
                              hipStream_t stream) {
  const float* x = (const float*)d_in[0];
  const float* w = (const float*)d_in[1];
  float* out = (float*)d_out;
  (void)in_sizes; (void)n_in; (void)out_size; (void)d_ws; (void)ws_size;
  dim3 grid(NWGS);
  dim3 block(1024);
  hipLaunchKernelGGL(linear_irreps_kernel, grid, block, 0, stream, x, w, out);
}